// Round 1
// baseline (229.951 us; speedup 1.0000x reference)
//
#include <hip/hip_runtime.h>
#include <math.h>

// Problem constants: B=4, N=512, C_IN=256, D=256, K=20
// rows = B*N = 2048
//
// ws layout (float offsets):
//   WtL [0, 65536)          W_l transposed [c][d]
//   WtR [65536, 131072)
//   XL  [131072, 655360)    x @ W_l^T + b_l   [2048][256]
//   XR  [655360, 1179648)
//   Av  [1179648, 1181696)  A_i = dot(att, XL[i])
//   Bv  [1181696, 1183744)  B_j = dot(att, XR[j])
//
// out layout (float): [0,40960) index_i, [40960,81920) index_j, [81920,122880) attention

__global__ __launch_bounds__(256) void k_transpose(const float* __restrict__ Wl,
                                                   const float* __restrict__ Wr,
                                                   float* __restrict__ WtL,
                                                   float* __restrict__ WtR) {
    const int d = blockIdx.x;      // 0..255 (row of W)
    const int c = threadIdx.x;     // 0..255 (col of W) — coalesced read
    if (blockIdx.y == 0) WtL[c * 256 + d] = Wl[d * 256 + c];
    else                 WtR[c * 256 + d] = Wr[d * 256 + c];
}

// One wg per 8 rows of x. Thread t owns output feature d=t for all 8 rows.
__global__ __launch_bounds__(256) void k_proj(const float* __restrict__ x,
        const float* __restrict__ WtL, const float* __restrict__ WtR,
        const float* __restrict__ bl, const float* __restrict__ br,
        const float* __restrict__ att,
        float* __restrict__ XL, float* __restrict__ XR,
        float* __restrict__ Av, float* __restrict__ Bv) {
    __shared__ float xs[8 * 256];   // 8 rows of x
    __shared__ float red[64];       // cross-wave reduction scratch [r][L/R][wave]
    const int tid = threadIdx.x;
    const int R = blockIdx.x * 8;

    // stage 8 rows (2048 floats) coalesced
    const float4* xg = (const float4*)(x + (size_t)R * 256);
    float4* xs4 = (float4*)xs;
    xs4[tid] = xg[tid];
    xs4[tid + 256] = xg[tid + 256];
    __syncthreads();

    float accL[8], accR[8];
#pragma unroll
    for (int r = 0; r < 8; ++r) { accL[r] = 0.f; accR[r] = 0.f; }

    for (int c4 = 0; c4 < 64; ++c4) {
        const int c = c4 * 4;
        // coalesced: lane t reads Wt[c][t]
        const float wl0 = WtL[(c + 0) * 256 + tid];
        const float wl1 = WtL[(c + 1) * 256 + tid];
        const float wl2 = WtL[(c + 2) * 256 + tid];
        const float wl3 = WtL[(c + 3) * 256 + tid];
        const float wr0 = WtR[(c + 0) * 256 + tid];
        const float wr1 = WtR[(c + 1) * 256 + tid];
        const float wr2 = WtR[(c + 2) * 256 + tid];
        const float wr3 = WtR[(c + 3) * 256 + tid];
#pragma unroll
        for (int r = 0; r < 8; ++r) {
            const float4 xv = *(const float4*)&xs[r * 256 + c];  // LDS broadcast
            accL[r] = fmaf(xv.x, wl0, accL[r]);
            accL[r] = fmaf(xv.y, wl1, accL[r]);
            accL[r] = fmaf(xv.z, wl2, accL[r]);
            accL[r] = fmaf(xv.w, wl3, accL[r]);
            accR[r] = fmaf(xv.x, wr0, accR[r]);
            accR[r] = fmaf(xv.y, wr1, accR[r]);
            accR[r] = fmaf(xv.z, wr2, accR[r]);
            accR[r] = fmaf(xv.w, wr3, accR[r]);
        }
    }

    const float blv = bl[tid], brv = br[tid], atv = att[tid];
    float pa[8], pb[8];
#pragma unroll
    for (int r = 0; r < 8; ++r) {
        const float xlv = accL[r] + blv;
        const float xrv = accR[r] + brv;
        XL[(size_t)(R + r) * 256 + tid] = xlv;   // coalesced
        XR[(size_t)(R + r) * 256 + tid] = xrv;
        pa[r] = atv * xlv;
        pb[r] = atv * xrv;
    }
    // A_i / B_j: reduce over 256 threads (d)
#pragma unroll
    for (int r = 0; r < 8; ++r) {
#pragma unroll
        for (int off = 32; off; off >>= 1) {
            pa[r] += __shfl_xor(pa[r], off);
            pb[r] += __shfl_xor(pb[r], off);
        }
    }
    const int lane = tid & 63, wv = tid >> 6;
    if (lane == 0) {
#pragma unroll
        for (int r = 0; r < 8; ++r) {
            red[r * 8 + wv] = pa[r];
            red[r * 8 + 4 + wv] = pb[r];
        }
    }
    __syncthreads();
    if (tid < 16) {
        const int r = tid >> 1, wh = tid & 1;
        const float* p = &red[r * 8 + wh * 4];
        const float s = p[0] + p[1] + p[2] + p[3];
        if (wh == 0) Av[R + r] = s; else Bv[R + r] = s;
    }
}

// One wg (256 thr) per 8 query rows. Thread = one j per 256-wide j-tile.
// alpha[i][j] = 0.6*(A_i + B_j) + 0.4*sum_d att_d*|xl[i][d]+xr[j][d]|
__global__ __launch_bounds__(256) void k_attn(const float* __restrict__ XL,
        const float* __restrict__ XR, const float* __restrict__ Av,
        const float* __restrict__ Bv, const float* __restrict__ att,
        float* __restrict__ out) {
    __shared__ float xrt[256 * 32];   // 32 KB: xr tile [j=256][d=32], 16B-XOR-swizzled
    __shared__ float alpha[8 * 512];  // 16 KB
    const int tid = threadIdx.x;
    const int g = blockIdx.x;
    // XCD swizzle: 2 XCDs per batch so XR[b] (2 MB) stays L2-resident
    const int b = (g & 7) >> 1;
    const int t64 = ((g >> 3) << 1) | (g & 1);  // 0..63
    const int R = b * 512 + t64 * 8;            // global row base of our 8 i's
    const float* XRb = XR + (size_t)b * 512 * 256;
    const float* XLr = XL + (size_t)R * 256;    // wave-uniform -> s_load

    for (int jt = 0; jt < 512; jt += 256) {
        float acc[8];
#pragma unroll
        for (int i = 0; i < 8; ++i) acc[i] = 0.f;

        for (int dt = 0; dt < 256; dt += 32) {
            __syncthreads();
            // stage XR[jt..jt+255][dt..dt+31]: coalesced global reads,
            // swizzled conflict-free LDS writes
#pragma unroll
            for (int it = 0; it < 8; ++it) {
                const int f = it * 256 + tid;   // float4 index, 0..2047
                const int j = f >> 3;           // 8 float4 per row
                const int c4 = f & 7;
                const float4 v = *(const float4*)&XRb[(size_t)(jt + j) * 256 + dt + c4 * 4];
                const int sw = c4 ^ (j & 7);
                *(float4*)&xrt[j * 32 + sw * 4] = v;
            }
            __syncthreads();

            const int j = tid;
            const int swb = j & 7;
#pragma unroll
            for (int c4 = 0; c4 < 8; ++c4) {
                const float4 xr4 = *(const float4*)&xrt[j * 32 + ((c4 ^ swb) << 2)];
                const int d = dt + c4 * 4;
                const float a0 = att[d + 0], a1 = att[d + 1];
                const float a2 = att[d + 2], a3 = att[d + 3];
#pragma unroll
                for (int i = 0; i < 8; ++i) {
                    const float* xl = XLr + i * 256 + d;   // uniform -> scalar load
                    const float v0 = xl[0] + xr4.x;
                    const float v1 = xl[1] + xr4.y;
                    const float v2 = xl[2] + xr4.z;
                    const float v3 = xl[3] + xr4.w;
                    acc[i] = fmaf(a0, fabsf(v0), acc[i]);  // abs is a free VOP3 modifier
                    acc[i] = fmaf(a1, fabsf(v1), acc[i]);
                    acc[i] = fmaf(a2, fabsf(v2), acc[i]);
                    acc[i] = fmaf(a3, fabsf(v3), acc[i]);
                }
            }
        }
        const float Bj = Bv[b * 512 + jt + tid];
#pragma unroll
        for (int i = 0; i < 8; ++i) {
            float a = fmaf(0.4f, acc[i], 0.6f * (Av[R + i] + Bj));
            if (!isfinite(a)) a = 0.f;          // nan_to_num
            alpha[i * 512 + jt + tid] = a;
        }
    }
    __syncthreads();

    // top-20 + softmax: wave wv handles rows 2*wv, 2*wv+1
    const int lane = tid & 63;
    const int wv = tid >> 6;
    for (int ri = 0; ri < 2; ++ri) {
        const int i = wv * 2 + ri;
        float v[8];
#pragma unroll
        for (int t = 0; t < 8; ++t) v[t] = alpha[i * 512 + t * 64 + lane];
        float myval = 0.f, mmax = 0.f;
        int myidx = 0;
        for (int sel = 0; sel < 20; ++sel) {
            // lane-local argmax (strict > keeps lowest j on ties)
            float bv = v[0]; int bt = 0;
#pragma unroll
            for (int t = 1; t < 8; ++t) { if (v[t] > bv) { bv = v[t]; bt = t; } }
            int bj = bt * 64 + lane;
            // 64-lane butterfly argmax, tie-break: lower index wins (jax top_k)
#pragma unroll
            for (int off = 32; off; off >>= 1) {
                const float ov = __shfl_xor(bv, off);
                const int   oj = __shfl_xor(bj, off);
                if (ov > bv || (ov == bv && oj < bj)) { bv = ov; bj = oj; }
            }
            if (sel == 0) mmax = bv;
            if (lane == sel) { myval = bv; myidx = bj; }
            if ((bj & 63) == lane) {
                const int bt2 = bj >> 6;
#pragma unroll
                for (int t = 0; t < 8; ++t) if (t == bt2) v[t] = -INFINITY;
            }
        }
        // softmax over the 20 selected (sorted desc; mmax = element 0)
        const float e = (lane < 20) ? expf(myval - mmax) : 0.f;
        float s = e;
#pragma unroll
        for (int off = 32; off; off >>= 1) s += __shfl_xor(s, off);
        if (lane < 20) {
            const int r = R + i;
            const int base = r * 20 + lane;
            out[base] = (float)r;                          // index_i = i + b*N
            out[40960 + base] = (float)(b * 512 + myidx);  // index_j = topk idx + b*N
            out[81920 + base] = e / s;                     // attention
        }
    }
}

extern "C" void kernel_launch(void* const* d_in, const int* in_sizes, int n_in,
                              void* d_out, int out_size, void* d_ws, size_t ws_size,
                              hipStream_t stream) {
    const float* x   = (const float*)d_in[0];
    // d_in[1] edge_index, d_in[2] batch: unused by the reference output
    const float* Wl  = (const float*)d_in[3];
    const float* bl  = (const float*)d_in[4];
    const float* Wr  = (const float*)d_in[5];
    const float* br  = (const float*)d_in[6];
    const float* att = (const float*)d_in[7];

    float* ws  = (float*)d_ws;
    float* WtL = ws;
    float* WtR = ws + 65536;
    float* XL  = ws + 131072;
    float* XR  = ws + 655360;
    float* Av  = ws + 1179648;
    float* Bv  = ws + 1181696;
    float* out = (float*)d_out;

    k_transpose<<<dim3(256, 2), dim3(256), 0, stream>>>(Wl, Wr, WtL, WtR);
    k_proj<<<dim3(256), dim3(256), 0, stream>>>(x, WtL, WtR, bl, br, att, XL, XR, Av, Bv);
    k_attn<<<dim3(256), dim3(256), 0, stream>>>(XL, XR, Av, Bv, att, out);
}

// Round 2
// 138.735 us; speedup vs baseline: 1.6575x; 1.6575x over previous
//
#include <hip/hip_runtime.h>
#include <math.h>

// B=4, N=512, C=D=256, K=20, rows=2048
//
// ws layout (float offsets) — alpha overlaps Wt (used sequentially):
//   WtL   [0, 65536)         W_l^T [c][d]        (k_transpose -> k_proj)
//   WtR   [65536, 131072)
//   alpha [0, 1048576)       [row][512]          (k_pair -> k_topk, clobbers Wt)
//   XL    [1048576, +524288) [row][d]  row-major
//   XRt   [1572864, +524288) [b][d][j] d-major (transposed for coalesced k_pair reads)
//   Av    [2097152, +2048)   dot(att, XL[row])
//   Bv    [2099200, +2048)   dot(att, XR[row])
//
// out (float): [0,40960) index_i | [40960,81920) index_j | [81920,122880) attention

__global__ __launch_bounds__(256) void k_transpose(const float* __restrict__ Wl,
                                                   const float* __restrict__ Wr,
                                                   float* __restrict__ WtL,
                                                   float* __restrict__ WtR) {
    const int d = blockIdx.x, c = threadIdx.x;  // coalesced read of W[d][:]
    if (blockIdx.y == 0) WtL[c * 256 + d] = Wl[d * 256 + c];
    else                 WtR[c * 256 + d] = Wr[d * 256 + c];
}

// 512 wgs x 256 thr; wg = 4 rows, thread t = output feature d.
__global__ __launch_bounds__(256) void k_proj(const float* __restrict__ x,
        const float* __restrict__ WtL, const float* __restrict__ WtR,
        const float* __restrict__ bl, const float* __restrict__ br,
        const float* __restrict__ att,
        float* __restrict__ XL, float* __restrict__ XRt,
        float* __restrict__ Av, float* __restrict__ Bv) {
    __shared__ float xs[4 * 256];
    __shared__ float red[32];   // [r][side][wave]
    const int tid = threadIdx.x;
    const int R = blockIdx.x * 4;

    ((float4*)xs)[tid] = ((const float4*)(x + (size_t)R * 256))[tid];
    __syncthreads();

    float accL[4] = {0.f, 0.f, 0.f, 0.f}, accR[4] = {0.f, 0.f, 0.f, 0.f};
    for (int c = 0; c < 256; c += 4) {
        const float wl0 = WtL[(c + 0) * 256 + tid];
        const float wl1 = WtL[(c + 1) * 256 + tid];
        const float wl2 = WtL[(c + 2) * 256 + tid];
        const float wl3 = WtL[(c + 3) * 256 + tid];
        const float wr0 = WtR[(c + 0) * 256 + tid];
        const float wr1 = WtR[(c + 1) * 256 + tid];
        const float wr2 = WtR[(c + 2) * 256 + tid];
        const float wr3 = WtR[(c + 3) * 256 + tid];
#pragma unroll
        for (int r = 0; r < 4; ++r) {
            const float4 xv = *(const float4*)&xs[r * 256 + c];  // LDS broadcast
            accL[r] = fmaf(xv.x, wl0, accL[r]);
            accL[r] = fmaf(xv.y, wl1, accL[r]);
            accL[r] = fmaf(xv.z, wl2, accL[r]);
            accL[r] = fmaf(xv.w, wl3, accL[r]);
            accR[r] = fmaf(xv.x, wr0, accR[r]);
            accR[r] = fmaf(xv.y, wr1, accR[r]);
            accR[r] = fmaf(xv.z, wr2, accR[r]);
            accR[r] = fmaf(xv.w, wr3, accR[r]);
        }
    }

    const float blv = bl[tid], brv = br[tid], atv = att[tid];
    float xlv[4], xrv[4], pa[4], pb[4];
#pragma unroll
    for (int r = 0; r < 4; ++r) {
        xlv[r] = accL[r] + blv;
        xrv[r] = accR[r] + brv;
        XL[(size_t)(R + r) * 256 + tid] = xlv[r];  // coalesced
        pa[r] = atv * xlv[r];
        pb[r] = atv * xrv[r];
    }
    // transposed write: 4 consecutive j for fixed d=tid -> one float4
    const int b = R >> 9, jr = R & 511;
    *(float4*)&XRt[((size_t)(b * 256 + tid)) * 512 + jr] =
        make_float4(xrv[0], xrv[1], xrv[2], xrv[3]);

#pragma unroll
    for (int r = 0; r < 4; ++r) {
#pragma unroll
        for (int off = 32; off; off >>= 1) {
            pa[r] += __shfl_xor(pa[r], off);
            pb[r] += __shfl_xor(pb[r], off);
        }
    }
    const int lane = tid & 63, wv = tid >> 6;
    if (lane == 0) {
#pragma unroll
        for (int r = 0; r < 4; ++r) {
            red[r * 8 + wv] = pa[r];
            red[r * 8 + 4 + wv] = pb[r];
        }
    }
    __syncthreads();
    if (tid < 8) {
        const int r = tid >> 1, side = tid & 1;
        const float* p = &red[r * 8 + side * 4];
        const float s = p[0] + p[1] + p[2] + p[3];
        if (side == 0) Av[R + r] = s; else Bv[R + r] = s;
    }
}

// 512 wgs x 256 thr, NO LDS, NO barriers. wg = (b, 8 i-rows, half of j).
// alpha[i][j] = 0.6*(A_i+B_j) + 0.4*sum_d att_d*|xl[i][d]+xr[j][d]|
__global__ __launch_bounds__(256) void k_pair(const float* __restrict__ XL,
        const float* __restrict__ XRt, const float* __restrict__ Av,
        const float* __restrict__ Bv, const float* __restrict__ att,
        float* __restrict__ alpha) {
    const int tid = threadIdx.x;
    const int g = blockIdx.x;          // 0..511
    const int jh = g & 1;
    const int ig = g >> 1;             // 0..255
    const int b = ig >> 6;
    const int R = b * 512 + (ig & 63) * 8;
    const int j = jh * 256 + tid;      // 0..511 within batch

    const float* __restrict__ XLr = XL + (size_t)R * 256;           // uniform -> s_load
    const float* __restrict__ xrp = XRt + ((size_t)b * 256) * 512 + j;

    float acc[8];
#pragma unroll
    for (int i = 0; i < 8; ++i) acc[i] = 0.f;

    for (int d = 0; d < 256; d += 8) {
        float xr[8];
#pragma unroll
        for (int dd = 0; dd < 8; ++dd) xr[dd] = xrp[dd * 512];       // coalesced
#pragma unroll
        for (int dd = 0; dd < 8; ++dd) {
            const float a = att[d + dd];                             // uniform
#pragma unroll
            for (int i = 0; i < 8; ++i) {
                const float v = XLr[i * 256 + d + dd] + xr[dd];      // uniform xl
                acc[i] = fmaf(a, fabsf(v), acc[i]);                  // abs = free modifier
            }
        }
        xrp += 8 * 512;
    }

    const float Bj = Bv[b * 512 + j];
#pragma unroll
    for (int i = 0; i < 8; ++i) {
        float a = fmaf(0.4f, acc[i], 0.6f * (Av[R + i] + Bj));
        if (!isfinite(a)) a = 0.f;     // nan_to_num
        alpha[(size_t)(R + i) * 512 + j] = a;
    }
}

// 512 wgs x 256 thr; one wave per row. top-20 (jax tie-break) + softmax + output.
__global__ __launch_bounds__(256) void k_topk(const float* __restrict__ alpha,
                                              float* __restrict__ out) {
    const int lane = threadIdx.x & 63;
    const int row = blockIdx.x * 4 + (threadIdx.x >> 6);
    const float* ar = alpha + (size_t)row * 512;

    const float4 u0 = *(const float4*)&ar[lane * 8];
    const float4 u1 = *(const float4*)&ar[lane * 8 + 4];
    float v[8] = {u0.x, u0.y, u0.z, u0.w, u1.x, u1.y, u1.z, u1.w};  // j = lane*8 + t

    float myval = 0.f, mmax = 0.f;
    int myidx = 0;
    for (int sel = 0; sel < 20; ++sel) {
        float bv = v[0]; int bt = 0;
#pragma unroll
        for (int t = 1; t < 8; ++t) { if (v[t] > bv) { bv = v[t]; bt = t; } }
        int bj = lane * 8 + bt;
#pragma unroll
        for (int off = 32; off; off >>= 1) {   // butterfly argmax, lower j wins ties
            const float ov = __shfl_xor(bv, off);
            const int   oj = __shfl_xor(bj, off);
            if (ov > bv || (ov == bv && oj < bj)) { bv = ov; bj = oj; }
        }
        if (sel == 0) mmax = bv;
        if (lane == sel) { myval = bv; myidx = bj; }
        if ((bj >> 3) == lane) {
            const int bt2 = bj & 7;
#pragma unroll
            for (int t = 0; t < 8; ++t) if (t == bt2) v[t] = -INFINITY;
        }
    }
    const float e = (lane < 20) ? expf(myval - mmax) : 0.f;
    float s = e;
#pragma unroll
    for (int off = 32; off; off >>= 1) s += __shfl_xor(s, off);
    if (lane < 20) {
        const int base = row * 20 + lane;
        const int b = row >> 9;
        out[base] = (float)row;                        // index_i
        out[40960 + base] = (float)(b * 512 + myidx);  // index_j
        out[81920 + base] = e / s;                     // attention
    }
}

extern "C" void kernel_launch(void* const* d_in, const int* in_sizes, int n_in,
                              void* d_out, int out_size, void* d_ws, size_t ws_size,
                              hipStream_t stream) {
    const float* x   = (const float*)d_in[0];
    const float* Wl  = (const float*)d_in[3];
    const float* bl  = (const float*)d_in[4];
    const float* Wr  = (const float*)d_in[5];
    const float* br  = (const float*)d_in[6];
    const float* att = (const float*)d_in[7];

    float* ws    = (float*)d_ws;
    float* WtL   = ws;
    float* WtR   = ws + 65536;
    float* alpha = ws;                 // overlaps Wt (sequential use)
    float* XL    = ws + 1048576;
    float* XRt   = ws + 1572864;
    float* Av    = ws + 2097152;
    float* Bv    = ws + 2099200;
    float* out   = (float*)d_out;

    k_transpose<<<dim3(256, 2), dim3(256), 0, stream>>>(Wl, Wr, WtL, WtR);
    k_proj<<<dim3(512), dim3(256), 0, stream>>>(x, WtL, WtR, bl, br, att, XL, XRt, Av, Bv);
    k_pair<<<dim3(512), dim3(256), 0, stream>>>(XL, XRt, Av, Bv, att, alpha);
    k_topk<<<dim3(512), dim3(256), 0, stream>>>(alpha, out);
}